// Round 1
// baseline (127.648 us; speedup 1.0000x reference)
//
#include <hip/hip_runtime.h>
#include <stdint.h>

typedef int   int4v   __attribute__((ext_vector_type(4)));
typedef float float4v __attribute__((ext_vector_type(4)));

static constexpr int DIM = 4096;   // N = IN = OUT
static constexpr int BT  = 128;    // output tile (M and N)
static constexpr int BK  = 128;    // K-step in int8 bytes (2 MFMA k-steps of 64)

// ---------------- quantization kernels ----------------
// q = clamp(rint(x/s) + zp, 0, 255); store (q - zp) as signed int8.
// zp == 128 here, so q - zp fits int8 exactly.

__global__ __launch_bounds__(256) void quant_act_kernel(
    const float* __restrict__ x, const float* __restrict__ s_ptr,
    const int* __restrict__ zp_ptr, int* __restrict__ out, int n4) {
  const float s  = s_ptr[0];
  const int   zp = zp_ptr[0];
  int idx    = blockIdx.x * blockDim.x + threadIdx.x;
  int stride = gridDim.x * blockDim.x;
  for (int i = idx; i < n4; i += stride) {
    float4v v = reinterpret_cast<const float4v*>(x)[i];
    int packed = 0;
#pragma unroll
    for (int j = 0; j < 4; ++j) {
      int q = (int)rintf(v[j] / s) + zp;   // rint = round-half-even, matches jnp.round
      q = min(max(q, 0), 255);
      q -= zp;
      packed |= (q & 255) << (8 * j);
    }
    out[i] = packed;
  }
}

__global__ __launch_bounds__(256) void quant_wgt_kernel(
    const float* __restrict__ w, const float* __restrict__ ws,
    const int* __restrict__ wzp, int* __restrict__ out, int n4) {
  int idx    = blockIdx.x * blockDim.x + threadIdx.x;
  int stride = gridDim.x * blockDim.x;
  for (int i = idx; i < n4; i += stride) {
    const int row = i >> 10;               // 1024 float4 per 4096-wide row
    const float s = ws[row];
    const int  zp = wzp[row];
    float4v v = reinterpret_cast<const float4v*>(w)[i];
    int packed = 0;
#pragma unroll
    for (int j = 0; j < 4; ++j) {
      int q = (int)rintf(v[j] / s) + zp;
      q = min(max(q, 0), 255);
      q -= zp;
      packed |= (q & 255) << (8 * j);
    }
    out[i] = packed;
  }
}

// ---------------- int8 GEMM (m97-structure, 128^2 tile, 4 waves) ----------------
// C[n][o] = sa*ws[o] * sum_k A8[n][k]*B8[o][k] + bias[o]
// A8: [DIM][DIM] int8 row-major; B8: [DIM][DIM] int8 row-major (weight layout, K contiguous).

__global__ __launch_bounds__(256) void gemm_i8_kernel(
    const signed char* __restrict__ A, const signed char* __restrict__ B,
    const float* __restrict__ s_act, const float* __restrict__ w_scale,
    const float* __restrict__ bias, float* __restrict__ C) {
  __shared__ signed char lA[BT * BK];   // 16 KB, linear [128][128] int8
  __shared__ signed char lB[BT * BK];   // 16 KB

  const int tid  = threadIdx.x;
  const int wave = tid >> 6;
  const int lane = tid & 63;
  const int wr = wave >> 1, wc = wave & 1;     // 2x2 wave grid, 64x64 per wave
  const int l15 = lane & 15, lhi = lane >> 4;

  const int tileM = blockIdx.y * BT;
  const int tileN = blockIdx.x * BT;

  // staging: chunk c covers LDS bytes [c*1024, c*1024+1024) = rows [c*8, c*8+8)
  // global_load_lds writes lane l at (wave-uniform base) + l*16
  const int srow  = lane >> 3;          // 0..7: row within chunk
  const int scolb = (lane & 7) << 4;    // 0..112: byte col within 128-byte row

  int4v acc[4][4] = {};

  const int nkt = DIM / BK;             // 32
  for (int kt = 0; kt < nkt; ++kt) {
    __syncthreads();                    // previous iter's LDS reads done
#pragma unroll
    for (int i = 0; i < 4; ++i) {
      const int c = (wave << 2) + i;
      const long ga = (long)(tileM + c * 8 + srow) * DIM + kt * BK + scolb;
      const long gb = (long)(tileN + c * 8 + srow) * DIM + kt * BK + scolb;
      __builtin_amdgcn_global_load_lds(
          (const __attribute__((address_space(1))) void*)(A + ga),
          (__attribute__((address_space(3))) void*)(lA + c * 1024), 16, 0, 0);
      __builtin_amdgcn_global_load_lds(
          (const __attribute__((address_space(1))) void*)(B + gb),
          (__attribute__((address_space(3))) void*)(lB + c * 1024), 16, 0, 0);
    }
    __syncthreads();                    // drains vmcnt -> LDS tile ready
#pragma unroll
    for (int kk = 0; kk < BK / 64; ++kk) {
      int4v af[4], bf[4];
#pragma unroll
      for (int m = 0; m < 4; ++m) {
        const int r = wr * 64 + m * 16 + l15;
        af[m] = *reinterpret_cast<const int4v*>(lA + r * BK + kk * 64 + lhi * 16);
      }
#pragma unroll
      for (int n = 0; n < 4; ++n) {
        const int r = wc * 64 + n * 16 + l15;
        bf[n] = *reinterpret_cast<const int4v*>(lB + r * BK + kk * 64 + lhi * 16);
      }
#pragma unroll
      for (int m = 0; m < 4; ++m)
#pragma unroll
        for (int n = 0; n < 4; ++n)
          acc[m][n] = __builtin_amdgcn_mfma_i32_16x16x64_i8(af[m], bf[n], acc[m][n], 0, 0, 0);
    }
  }

  // epilogue: C/D layout col = lane&15, row = (lane>>4)*4 + j  (verified m89/m91)
  const float sa = s_act[0];
#pragma unroll
  for (int n = 0; n < 4; ++n) {
    const int col = tileN + wc * 64 + n * 16 + l15;
    const float sc = sa * w_scale[col];
    const float bs = bias[col];
#pragma unroll
    for (int m = 0; m < 4; ++m) {
      const int rbase = tileM + wr * 64 + m * 16 + lhi * 4;
#pragma unroll
      for (int j = 0; j < 4; ++j) {
        C[(long)(rbase + j) * DIM + col] = (float)acc[m][n][j] * sc + bs;
      }
    }
  }
}

// ---------------- launch ----------------
extern "C" void kernel_launch(void* const* d_in, const int* in_sizes, int n_in,
                              void* d_out, int out_size, void* d_ws, size_t ws_size,
                              hipStream_t stream) {
  const float* x    = (const float*)d_in[0];
  const float* w    = (const float*)d_in[1];
  const float* bias = (const float*)d_in[2];
  const float* a_s  = (const float*)d_in[3];
  const int*   a_zp = (const int*)d_in[4];
  const float* w_s  = (const float*)d_in[5];
  const int*   w_zp = (const int*)d_in[6];
  float* out = (float*)d_out;

  // workspace: 16 MB quantized activations + 16 MB quantized weights
  signed char* a8 = (signed char*)d_ws;
  signed char* b8 = a8 + (size_t)DIM * DIM;

  const int n4 = DIM * DIM / 4;
  quant_act_kernel<<<2048, 256, 0, stream>>>(x, a_s, a_zp, (int*)a8, n4);
  quant_wgt_kernel<<<2048, 256, 0, stream>>>(w, w_s, w_zp, (int*)b8, n4);

  dim3 grid(DIM / BT, DIM / BT);   // 32 x 32 tiles
  gemm_i8_kernel<<<grid, 256, 0, stream>>>(a8, b8, a_s, w_s, bias, out);
}

// Round 2
// 97.283 us; speedup vs baseline: 1.3121x; 1.3121x over previous
//
#include <hip/hip_runtime.h>
#include <stdint.h>

typedef int   int4v   __attribute__((ext_vector_type(4)));
typedef float float4v __attribute__((ext_vector_type(4)));

static constexpr int DIM = 4096;          // N = IN = OUT
static constexpr int BM  = 256, BN = 256; // block tile
static constexpr int BK  = 128;           // K-step bytes (2 MFMA k-steps of K=64)
static constexpr int NKT = DIM / BK;      // 32

// ---------------- quantization kernels ----------------
__global__ __launch_bounds__(256) void quant_act_kernel(
    const float* __restrict__ x, const float* __restrict__ s_ptr,
    const int* __restrict__ zp_ptr, int* __restrict__ out, int n4) {
  const float s  = s_ptr[0];
  const int   zp = zp_ptr[0];
  int idx    = blockIdx.x * blockDim.x + threadIdx.x;
  int stride = gridDim.x * blockDim.x;
  for (int i = idx; i < n4; i += stride) {
    float4v v = reinterpret_cast<const float4v*>(x)[i];
    int packed = 0;
#pragma unroll
    for (int j = 0; j < 4; ++j) {
      int q = (int)rintf(v[j] / s) + zp;
      q = min(max(q, 0), 255);
      q -= zp;
      packed |= (q & 255) << (8 * j);
    }
    out[i] = packed;
  }
}

__global__ __launch_bounds__(256) void quant_wgt_kernel(
    const float* __restrict__ w, const float* __restrict__ ws,
    const int* __restrict__ wzp, int* __restrict__ out, int n4) {
  int idx    = blockIdx.x * blockDim.x + threadIdx.x;
  int stride = gridDim.x * blockDim.x;
  for (int i = idx; i < n4; i += stride) {
    const int row = i >> 10;
    const float s = ws[row];
    const int  zp = wzp[row];
    float4v v = reinterpret_cast<const float4v*>(w)[i];
    int packed = 0;
#pragma unroll
    for (int j = 0; j < 4; ++j) {
      int q = (int)rintf(v[j] / s) + zp;
      q = min(max(q, 0), 255);
      q -= zp;
      packed |= (q & 255) << (8 * j);
    }
    out[i] = packed;
  }
}

// ---------------- int8 GEMM: 256^2 tile, 8 waves, 4-phase/K-tile, dbuf + swizzle ----------------
// C[n][o] = sa*ws[o] * sum_k A8[n][k]*B8[o][k] + bias[o]

#define PHASE_MFMA(MH, NH)                                                    \
  __builtin_amdgcn_s_barrier();                                               \
  asm volatile("s_waitcnt lgkmcnt(0)" ::: "memory");                          \
  __builtin_amdgcn_s_setprio(1);                                              \
  _Pragma("unroll") for (int kk = 0; kk < 2; ++kk)                            \
  _Pragma("unroll") for (int m = 0; m < 4; ++m)                               \
  _Pragma("unroll") for (int n = 0; n < 2; ++n)                               \
      acc[(MH)*4 + m][(NH)*2 + n] = __builtin_amdgcn_mfma_i32_16x16x64_i8(    \
          af[m][kk], bf[(NH)*2 + n][kk], acc[(MH)*4 + m][(NH)*2 + n], 0,0,0); \
  __builtin_amdgcn_s_setprio(0);                                              \
  __builtin_amdgcn_s_barrier();

__global__ __launch_bounds__(512) void gemm_i8_8ph(
    const signed char* __restrict__ A, const signed char* __restrict__ B,
    const float* __restrict__ s_act, const float* __restrict__ w_scale,
    const float* __restrict__ bias, float* __restrict__ C) {
  extern __shared__ signed char smem[];  // 2 buffers x (A 32K + B 32K) = 128 KiB

  const int tid  = threadIdx.x;
  const int w    = tid >> 6;            // wave 0..7
  const int lane = tid & 63;
  const int wr = w >> 2, wc = w & 3;    // 2 x 4 wave grid; wave tile 128x64
  const int l15 = lane & 15, lhi = lane >> 4;
  const int swk = (l15 & 7) << 4;       // read-side XOR swizzle key

  const int srow = lane >> 3;                           // staging row within 8-row chunk
  const int scol = ((lane & 7) ^ (lane >> 3)) << 4;     // pre-swizzled global col (both-sides rule)

  const int tileM = blockIdx.y * BM;
  const int tileN = blockIdx.x * BN;

  // stage one 8-row x 128B chunk (1 KiB) of next tile; LDS dest linear, global src pre-swizzled
  auto stageA = [&](int i, int ktn, signed char* aL) {
    const int c = 4 * w + i;
    const size_t g = (size_t)(tileM + c * 8 + srow) * DIM + (size_t)ktn * BK + scol;
    __builtin_amdgcn_global_load_lds(
        (const __attribute__((address_space(1))) void*)(A + g),
        (__attribute__((address_space(3))) void*)(aL + c * 1024), 16, 0, 0);
  };
  auto stageB = [&](int i, int ktn, signed char* bL) {
    const int c = 4 * w + i;
    const size_t g = (size_t)(tileN + c * 8 + srow) * DIM + (size_t)ktn * BK + scol;
    __builtin_amdgcn_global_load_lds(
        (const __attribute__((address_space(1))) void*)(B + g),
        (__attribute__((address_space(3))) void*)(bL + c * 1024), 16, 0, 0);
  };
  // swizzled fragment reads
  auto rdA = [&](const signed char* aL, int mh, int m, int kk) -> int4v {
    const int r = wr * 128 + (mh * 4 + m) * 16 + l15;
    return *(const int4v*)(aL + r * BK + ((kk * 64 + lhi * 16) ^ swk));
  };
  auto rdB = [&](const signed char* bL, int nidx, int kk) -> int4v {
    const int r = wc * 64 + nidx * 16 + l15;
    return *(const int4v*)(bL + r * BK + ((kk * 64 + lhi * 16) ^ swk));
  };

  int4v acc[8][4] = {};
  int4v af[4][2];   // A frags for current m-half
  int4v bf[4][2];   // B frags for all 4 n (persist across phases of a K-tile)

  // prologue: stage all of tile 0 into buffer 0
  {
    signed char* aL = smem;
    signed char* bL = smem + 32768;
#pragma unroll
    for (int i = 0; i < 4; ++i) { stageA(i, 0, aL); stageB(i, 0, bL); }
  }
  asm volatile("s_waitcnt vmcnt(0)" ::: "memory");
  __builtin_amdgcn_s_barrier();

  for (int kt = 0; kt < NKT; ++kt) {
    signed char* aL = smem + (kt & 1) * 65536;
    signed char* bL = aL + 32768;
    signed char* aN = smem + ((kt + 1) & 1) * 65536;
    signed char* bN = aN + 32768;
    const int ktn = (kt + 1 < NKT) ? kt + 1 : kt;  // last iter re-stages (drained, unused)

    // ---- phase 1: read A(mh0), B(n0..1); stage 3 A-chunks; MFMA quadrant (0,0)
#pragma unroll
    for (int m = 0; m < 4; ++m) { af[m][0] = rdA(aL, 0, m, 0); af[m][1] = rdA(aL, 0, m, 1); }
#pragma unroll
    for (int n = 0; n < 2; ++n) { bf[n][0] = rdB(bL, n, 0); bf[n][1] = rdB(bL, n, 1); }
    stageA(0, ktn, aN); stageA(1, ktn, aN); stageA(2, ktn, aN);
    PHASE_MFMA(0, 0)

    // ---- phase 2: read B(n2..3); stage A3 + 2 B-chunks; MFMA quadrant (0,1)
#pragma unroll
    for (int n = 2; n < 4; ++n) { bf[n][0] = rdB(bL, n, 0); bf[n][1] = rdB(bL, n, 1); }
    stageA(3, ktn, aN); stageB(0, ktn, bN); stageB(1, ktn, bN);
    PHASE_MFMA(0, 1)

    // ---- phase 3: read A(mh1); stage last 2 B-chunks; MFMA quadrant (1,0)
#pragma unroll
    for (int m = 0; m < 4; ++m) { af[m][0] = rdA(aL, 1, m, 0); af[m][1] = rdA(aL, 1, m, 1); }
    stageB(2, ktn, bN); stageB(3, ktn, bN);
    PHASE_MFMA(1, 0)

    // ---- phase 4: no reads/stages; MFMA quadrant (1,1); drain staging before buffer swap
    __builtin_amdgcn_s_setprio(1);
#pragma unroll
    for (int kk = 0; kk < 2; ++kk)
#pragma unroll
      for (int m = 0; m < 4; ++m)
#pragma unroll
        for (int n = 0; n < 2; ++n)
          acc[4 + m][2 + n] = __builtin_amdgcn_mfma_i32_16x16x64_i8(
              af[m][kk], bf[2 + n][kk], acc[4 + m][2 + n], 0, 0, 0);
    __builtin_amdgcn_s_setprio(0);
    asm volatile("s_waitcnt vmcnt(0)" ::: "memory");  // next buffer fully landed
    __builtin_amdgcn_s_barrier();
  }

  // ---- epilogue: C/D layout col=lane&15, row=(lane>>4)*4+j
  const float sa = s_act[0];
#pragma unroll
  for (int n = 0; n < 4; ++n) {
    const int col = tileN + wc * 64 + n * 16 + l15;
    const float sc = sa * w_scale[col];
    const float bs = bias[col];
#pragma unroll
    for (int m = 0; m < 8; ++m) {
      const int rbase = tileM + wr * 128 + m * 16 + lhi * 4;
#pragma unroll
      for (int j = 0; j < 4; ++j)
        C[(size_t)(rbase + j) * DIM + col] = (float)acc[m][n][j] * sc + bs;
    }
  }
}

// ---------------- launch ----------------
extern "C" void kernel_launch(void* const* d_in, const int* in_sizes, int n_in,
                              void* d_out, int out_size, void* d_ws, size_t ws_size,
                              hipStream_t stream) {
  const float* x    = (const float*)d_in[0];
  const float* w    = (const float*)d_in[1];
  const float* bias = (const float*)d_in[2];
  const float* a_s  = (const float*)d_in[3];
  const int*   a_zp = (const int*)d_in[4];
  const float* w_s  = (const float*)d_in[5];
  const int*   w_zp = (const int*)d_in[6];
  float* out = (float*)d_out;

  signed char* a8 = (signed char*)d_ws;
  signed char* b8 = a8 + (size_t)DIM * DIM;

  const int n4 = DIM * DIM / 4;
  quant_act_kernel<<<2048, 256, 0, stream>>>(x, a_s, a_zp, (int*)a8, n4);
  quant_wgt_kernel<<<2048, 256, 0, stream>>>(w, w_s, w_zp, (int*)b8, n4);

  (void)hipFuncSetAttribute((const void*)gemm_i8_8ph,
                            hipFuncAttributeMaxDynamicSharedMemorySize, 131072);
  dim3 grid(DIM / BN, DIM / BM);  // 16 x 16 = 256 blocks (1 per CU)
  gemm_i8_8ph<<<grid, 512, 131072, stream>>>(a8, b8, a_s, w_s, bias, out);
}